// Round 15
// baseline (94.908 us; speedup 1.0000x reference)
//
#include <hip/hip_runtime.h>

#define BB 4
#define CC 256
#define NN 4096
#define II 128
#define NSPLIT 4
#define KVH (NN / NSPLIT)   // 1024 KV rows per split
#define NT (KVH / 64)       // 16 tiles per split
#define LOG2E 1.4426950408889634f

typedef float f32x4 __attribute__((ext_vector_type(4)));
typedef _Float16 f16x8 __attribute__((ext_vector_type(8)));

static __device__ __forceinline__ unsigned short f2h(float f) {
    _Float16 h = (_Float16)f;
    return __builtin_bit_cast(unsigned short, h);
}
static __device__ __forceinline__ float h2f(unsigned short s) {
    return (float)__builtin_bit_cast(_Float16, s);
}
static __device__ __forceinline__ unsigned int pack2h(float a, float b) {
    return (unsigned int)f2h(a) | ((unsigned int)f2h(b) << 16);
}
static __device__ __forceinline__ unsigned int cvt2h(float a, float b) {
    return __builtin_bit_cast(unsigned int, __builtin_amdgcn_cvt_pkrtz(a, b));
}
#define M3(a, b, c) fmaxf(fmaxf((a), (b)), (c))

// ---------------- projection: x staged ONCE, 3 mats sequential in K-loop ----------------
// grid (NN/32, BB). Same MFMA k-order as the per-mat proj -> bit-identical outputs.
__global__ __launch_bounds__(256) void proj_kernel(
    const float* __restrict__ x,
    const float* __restrict__ w_th, const float* __restrict__ b_th,
    const float* __restrict__ w_ph, const float* __restrict__ b_ph,
    const float* __restrict__ w_g,  const float* __restrict__ b_g,
    const float* __restrict__ w_out,
    unsigned short* __restrict__ Qb, unsigned short* __restrict__ Kb,
    unsigned short* __restrict__ Vt, unsigned short* __restrict__ Wo)
{
    __shared__ char lds[40960];   // xl [32n][512B] 16KB @0 | wl3 [3][128][64B] 24KB @16384

    int tid = threadIdx.x;
    int w = tid >> 6, l = tid & 63, g = l >> 4, cl = l & 15;
    int b = blockIdx.y, n0 = blockIdx.x * 32;
    const float* wp0 = w_th; const float* wp1 = w_ph; const float* wp2 = w_g;
    const float* xb = x + (size_t)b * CC * NN;

    // ---- stage x once: [32 n][256 c] fp16, 512B rows, XOR swz ((n&7)<<4) ----
    {
        int cp = tid >> 2, nch = tid & 3;
        #pragma unroll
        for (int h = 0; h < 2; ++h) {
            int cpp = h * 64 + cp;   // c-pair index, c = 2*cpp
            const float* xs = xb + (size_t)(2 * cpp) * NN + n0 + nch * 8;
            float4 a0 = *(const float4*)xs;
            float4 a1 = *(const float4*)(xs + 4);
            float4 b0 = *(const float4*)(xs + NN);
            float4 b1 = *(const float4*)(xs + NN + 4);
            float lo[8] = {a0.x, a0.y, a0.z, a0.w, a1.x, a1.y, a1.z, a1.w};
            float hi[8] = {b0.x, b0.y, b0.z, b0.w, b1.x, b1.y, b1.z, b1.w};
            #pragma unroll
            for (int t = 0; t < 8; ++t) {
                int n = nch * 8 + t;
                *(unsigned int*)(lds + n * 512 + ((cpp * 4) ^ ((n & 7) << 4))) = pack2h(lo[t], hi[t]);
            }
        }
    }

    f32x4 acc[3][2][2];
    #pragma unroll
    for (int m = 0; m < 3; ++m)
        #pragma unroll
        for (int it = 0; it < 2; ++it)
            #pragma unroll
            for (int nt = 0; nt < 2; ++nt) acc[m][it][nt] = (f32x4){0.f, 0.f, 0.f, 0.f};

    for (int c0 = 0; c0 < CC; c0 += 32) {
        __syncthreads();   // x visible (first iter); prev MFMA done before wl overwrite (later)
        // stage w chunk for all 3 mats: [mat][128 i][32 c] fp16, 64B rows, swz ((ir&3)<<4)
        #pragma unroll
        for (int r = 0; r < 6; ++r) {
            const int mat = r >> 1;
            int u = (r & 1) * 256 + tid;
            int ir = u >> 2, ch = u & 3;
            const float* wsrc = (mat == 0 ? wp0 : mat == 1 ? wp1 : wp2) + ir * CC + c0 + ch * 8;
            float4 a = *(const float4*)wsrc;
            float4 bq = *(const float4*)(wsrc + 4);
            union { unsigned int uu[4]; uint4 q; } pk;
            pk.uu[0] = pack2h(a.x, a.y);   pk.uu[1] = pack2h(a.z, a.w);
            pk.uu[2] = pack2h(bq.x, bq.y); pk.uu[3] = pack2h(bq.z, bq.w);
            *(uint4*)(lds + 16384 + mat * 8192 + ir * 64 + ((ch * 16) ^ ((ir & 3) << 4))) = pk.q;
        }
        __syncthreads();
        // MFMA: wave covers i in [w*32, w*32+32), n in [0,32)
        f16x8 bf[2];
        #pragma unroll
        for (int nt = 0; nt < 2; ++nt) {
            int n = nt * 16 + cl;
            bf[nt] = *(const f16x8*)(lds + n * 512 + ((c0 * 2 + g * 16) ^ ((n & 7) << 4)));
        }
        #pragma unroll
        for (int m = 0; m < 3; ++m) {
            f16x8 af[2];
            #pragma unroll
            for (int it = 0; it < 2; ++it) {
                int i = w * 32 + it * 16 + cl;
                af[it] = *(const f16x8*)(lds + 16384 + m * 8192 + i * 64 + ((g * 16) ^ ((i & 3) << 4)));
            }
            #pragma unroll
            for (int it = 0; it < 2; ++it)
                #pragma unroll
                for (int nt = 0; nt < 2; ++nt)
                    acc[m][it][nt] = __builtin_amdgcn_mfma_f32_16x16x32_f16(af[it], bf[nt], acc[m][it][nt], 0, 0, 0);
        }
    }

    float bv[3][2][4];
    #pragma unroll
    for (int m = 0; m < 3; ++m) {
        const float* bp = (m == 0) ? b_th : (m == 1) ? b_ph : b_g;
        #pragma unroll
        for (int it = 0; it < 2; ++it)
            #pragma unroll
            for (int r = 0; r < 4; ++r) bv[m][it][r] = bp[w * 32 + it * 16 + 4 * g + r];
    }

    __syncthreads();   // all MFMA reads done; LDS reusable
    // park: Q @0 [32n][256B], K @8192 [32n][256B], V @16384 [128i][64B]
    #pragma unroll
    for (int m = 0; m < 2; ++m) {
        float scale = (m == 0) ? LOG2E : 1.0f;
        char* pk = lds + m * 8192;
        #pragma unroll
        for (int it = 0; it < 2; ++it)
            #pragma unroll
            for (int nt = 0; nt < 2; ++nt)
                #pragma unroll
                for (int r = 0; r < 4; r += 2) {
                    int n = nt * 16 + cl;
                    int i = w * 32 + it * 16 + 4 * g + r;
                    unsigned int v = pack2h((acc[m][it][nt][r] + bv[m][it][r]) * scale,
                                            (acc[m][it][nt][r + 1] + bv[m][it][r + 1]) * scale);
                    *(unsigned int*)(pk + n * 256 + ((i * 2) ^ ((n & 7) << 4))) = v;
                }
    }
    {
        char* pk = lds + 16384;
        #pragma unroll
        for (int it = 0; it < 2; ++it)
            #pragma unroll
            for (int nt = 0; nt < 2; ++nt)
                #pragma unroll
                for (int r = 0; r < 4; ++r) {
                    int i = w * 32 + it * 16 + 4 * g + r;
                    int n = nt * 16 + cl;
                    *(unsigned short*)(pk + i * 64 + ((n * 2) ^ ((i & 3) << 4))) =
                        f2h(acc[2][it][nt][r] + bv[2][it][r]);
                }
    }
    __syncthreads();
    // dense stores (XOR at read recovers logical chunk index)
    #pragma unroll
    for (int r2 = 0; r2 < 2; ++r2) {
        int u = r2 * 256 + tid;
        // Q/K: 32 n-rows x 16 chunks = 512
        int n = u >> 4, seg = u & 15;
        uint4 q0 = *(const uint4*)(lds + n * 256 + ((seg * 16) ^ ((n & 7) << 4)));
        *(uint4*)(Qb + (size_t)(b * NN + n0 + n) * II + seg * 8) = q0;
        uint4 q1 = *(const uint4*)(lds + 8192 + n * 256 + ((seg * 16) ^ ((n & 7) << 4)));
        *(uint4*)(Kb + (size_t)(b * NN + n0 + n) * II + seg * 8) = q1;
        // V: 128 i-rows x 4 chunks = 512  (R14 bug: was u>>1/u&1 -> OOB + cross-batch corruption)
        int i = u >> 2, ch = u & 3;
        uint4 q2 = *(const uint4*)(lds + 16384 + i * 64 + ((ch * 16) ^ ((i & 3) << 4)));
        *(uint4*)(Vt + (size_t)(b * II + i) * NN + n0 + ch * 8) = q2;
    }
    if (blockIdx.x == 0 && b == 0) {
        #pragma unroll
        for (int r = 0; r < 16; ++r) {
            int idx = (r * 256 + tid) * 8;
            float4 a = *(const float4*)(w_out + idx);
            float4 b4 = *(const float4*)(w_out + idx + 4);
            union { unsigned int uu[4]; uint4 q; } pw;
            pw.uu[0] = pack2h(a.x, a.y);   pw.uu[1] = pack2h(a.z, a.w);
            pw.uu[2] = pack2h(b4.x, b4.y); pw.uu[3] = pack2h(b4.z, b4.w);
            *(uint4*)&Wo[idx] = pw.q;
        }
    }
}

// ---------------- flash attention: 32 q/wave, dbuf LDS, ONE barrier per tile ----------------
// (unchanged: 55.5 µs, plateaued at 2 waves/SIMD — register-residency-capped)
__global__ __launch_bounds__(256, 2) void attn_kernel(
    const unsigned short* __restrict__ Qb,   // [B][N][II] fp16 (pre-scaled by log2e)
    const unsigned short* __restrict__ Kb,   // [B][N][II] fp16
    const unsigned short* __restrict__ Vb,   // [B][II][N] fp16
    unsigned short* __restrict__ Yp,         // [NSPLIT][B][N][II] fp16 normalized partial
    float2* __restrict__ ML)                 // [NSPLIT][B][N] {m,l} (base-2 domain)
{
    __shared__ unsigned short Ks[2][64 * 128];   // dbuf K (32 KB)
    __shared__ unsigned short Vs[2][128 * 64];   // dbuf V^T, permuted cols (32 KB)

    int tid = threadIdx.x;
    int w = tid >> 6, l = tid & 63, g = l >> 4, cl = l & 15;
    int id = blockIdx.x;
    int comb = (id & 7) * 2 + ((id >> 3) & 1);
    int b = comb >> 2, sp = comb & 3, qt = id >> 4;
    int qr0 = qt * 128;
    int m_base = sp * KVH;

    f16x8 qa0[4], qa1[4];
    {
        const unsigned short* qrow0 = Qb + (size_t)(b * NN + qr0 + w * 32 + cl) * II;
        const unsigned short* qrow1 = qrow0 + 16 * II;
        #pragma unroll
        for (int kc = 0; kc < 4; ++kc) {
            qa0[kc] = *(const f16x8*)(qrow0 + kc * 32 + g * 8);
            qa1[kc] = *(const f16x8*)(qrow1 + kc * 32 + g * 8);
        }
    }
    const f16x8 onesv = {(_Float16)1.f, (_Float16)1.f, (_Float16)1.f, (_Float16)1.f,
                         (_Float16)1.f, (_Float16)1.f, (_Float16)1.f, (_Float16)1.f};

    f32x4 yacc0[8], yacc1[8], lacc0, lacc1;
    #pragma unroll
    for (int it = 0; it < 8; ++it) {
        yacc0[it] = (f32x4){0.f, 0.f, 0.f, 0.f};
        yacc1[it] = (f32x4){0.f, 0.f, 0.f, 0.f};
    }
    lacc0 = (f32x4){0.f, 0.f, 0.f, 0.f};
    lacc1 = (f32x4){0.f, 0.f, 0.f, 0.f};
    float mrun0 = -1e30f, mrun1 = -1e30f;

    const unsigned short* kb = Kb + (size_t)(b * NN + m_base) * II;
    const unsigned short* vb = Vb + (size_t)b * II * NN + m_base;
    int krow = tid >> 4, kch = tid & 15;
    int vrow = tid >> 3, vch = tid & 7;
    int kswz = (kch ^ (krow & 7)) << 4;
    int vsw = (vrow & 7) << 4;
    int vc0 = ((vch >> 2) * 32 + (vch & 1) * 16 + ((vch >> 1) & 1) * 4) * 2;

    uint4 k0, k1, k2, k3, v0, v1, v2, v3;   // named regs (no PromoteAlloca)
    k0 = *(const uint4*)(kb + (size_t)(krow) * II + kch * 8);
    k1 = *(const uint4*)(kb + (size_t)(16 + krow) * II + kch * 8);
    k2 = *(const uint4*)(kb + (size_t)(32 + krow) * II + kch * 8);
    k3 = *(const uint4*)(kb + (size_t)(48 + krow) * II + kch * 8);
    v0 = *(const uint4*)(vb + (size_t)(vrow) * NN + vch * 8);
    v1 = *(const uint4*)(vb + (size_t)(32 + vrow) * NN + vch * 8);
    v2 = *(const uint4*)(vb + (size_t)(64 + vrow) * NN + vch * 8);
    v3 = *(const uint4*)(vb + (size_t)(96 + vrow) * NN + vch * 8);
    // publish tile 0 into buf 0 (visible after first barrier)
    {
        *(uint4*)((char*)Ks[0] + (krow) * 256 + kswz) = k0;
        *(uint4*)((char*)Ks[0] + (16 + krow) * 256 + kswz) = k1;
        *(uint4*)((char*)Ks[0] + (32 + krow) * 256 + kswz) = k2;
        *(uint4*)((char*)Ks[0] + (48 + krow) * 256 + kswz) = k3;
        uint2 lo, hi;
        lo.x = v0.x; lo.y = v0.y; hi.x = v0.z; hi.y = v0.w;
        *(uint2*)((char*)Vs[0] + (vrow) * 128 + (vc0 ^ vsw)) = lo;
        *(uint2*)((char*)Vs[0] + (vrow) * 128 + ((vc0 + 16) ^ vsw)) = hi;
        lo.x = v1.x; lo.y = v1.y; hi.x = v1.z; hi.y = v1.w;
        *(uint2*)((char*)Vs[0] + (32 + vrow) * 128 + (vc0 ^ vsw)) = lo;
        *(uint2*)((char*)Vs[0] + (32 + vrow) * 128 + ((vc0 + 16) ^ vsw)) = hi;
        lo.x = v2.x; lo.y = v2.y; hi.x = v2.z; hi.y = v2.w;
        *(uint2*)((char*)Vs[0] + (64 + vrow) * 128 + (vc0 ^ vsw)) = lo;
        *(uint2*)((char*)Vs[0] + (64 + vrow) * 128 + ((vc0 + 16) ^ vsw)) = hi;
        lo.x = v3.x; lo.y = v3.y; hi.x = v3.z; hi.y = v3.w;
        *(uint2*)((char*)Vs[0] + (96 + vrow) * 128 + (vc0 ^ vsw)) = lo;
        *(uint2*)((char*)Vs[0] + (96 + vrow) * 128 + ((vc0 + 16) ^ vsw)) = hi;
    }

    for (int t = 0; t < NT; ++t) {
        __syncthreads();   // buf[t&1] writes visible; all waves finished iter t-1
        const unsigned short* ksb = Ks[t & 1];
        const unsigned short* vsb = Vs[t & 1];
        unsigned short* kw = Ks[(t + 1) & 1];
        unsigned short* vw = Vs[(t + 1) & 1];
        bool more = (t + 1 < NT);
        if (more) {   // issue next tile's loads; latency hides under QK/softmax
            const unsigned short* kp = kb + (size_t)(t + 1) * 64 * II;
            const unsigned short* vp = vb + (size_t)(t + 1) * 64;
            k0 = *(const uint4*)(kp + (size_t)(krow) * II + kch * 8);
            k1 = *(const uint4*)(kp + (size_t)(16 + krow) * II + kch * 8);
            k2 = *(const uint4*)(kp + (size_t)(32 + krow) * II + kch * 8);
            k3 = *(const uint4*)(kp + (size_t)(48 + krow) * II + kch * 8);
            v0 = *(const uint4*)(vp + (size_t)(vrow) * NN + vch * 8);
            v1 = *(const uint4*)(vp + (size_t)(32 + vrow) * NN + vch * 8);
            v2 = *(const uint4*)(vp + (size_t)(64 + vrow) * NN + vch * 8);
            v3 = *(const uint4*)(vp + (size_t)(96 + vrow) * NN + vch * 8);
        }

        // ---- S^T = K Q^T for both q-groups, each K fragment read ONCE ----
        f32x4 s0[4], s1[4];
        #pragma unroll
        for (int mt = 0; mt < 4; ++mt) {
            s0[mt] = (f32x4){0.f, 0.f, 0.f, 0.f};
            s1[mt] = (f32x4){0.f, 0.f, 0.f, 0.f};
        }
        __builtin_amdgcn_s_setprio(1);
        #pragma unroll
        for (int mt = 0; mt < 4; ++mt) {
            int row = mt * 16 + cl;
            #pragma unroll
            for (int kc = 0; kc < 4; ++kc) {
                f16x8 kf = *(const f16x8*)((const char*)ksb + row * 256 + (((kc * 4 + g) ^ (row & 7)) << 4));
                s0[mt] = __builtin_amdgcn_mfma_f32_16x16x32_f16(kf, qa0[kc], s0[mt], 0, 0, 0);
                s1[mt] = __builtin_amdgcn_mfma_f32_16x16x32_f16(kf, qa1[kc], s1[mt], 0, 0, 0);
            }
        }
        __builtin_amdgcn_s_setprio(0);

        // write next K tile mid-stream (K regs die; different buffer than ksb)
        if (more) {
            *(uint4*)((char*)kw + (krow) * 256 + kswz) = k0;
            *(uint4*)((char*)kw + (16 + krow) * 256 + kswz) = k1;
            *(uint4*)((char*)kw + (32 + krow) * 256 + kswz) = k2;
            *(uint4*)((char*)kw + (48 + krow) * 256 + kswz) = k3;
        }

        // ---- softmax q-group 0 ----
        union { unsigned int u[4]; f16x8 v; } pb00, pb01, pb10, pb11;
        {
            float t0 = M3(s0[0][0], s0[0][1], s0[0][2]);
            float t1 = M3(s0[0][3], s0[1][0], s0[1][1]);
            float t2 = M3(s0[1][2], s0[1][3], s0[2][0]);
            float t3 = M3(s0[2][1], s0[2][2], s0[2][3]);
            float t4 = M3(s0[3][0], s0[3][1], s0[3][2]);
            float tmax = fmaxf(M3(t0, t1, t2), M3(t3, t4, s0[3][3]));
            tmax = fmaxf(tmax, __shfl_xor(tmax, 16));
            tmax = fmaxf(tmax, __shfl_xor(tmax, 32));
            if (!__all(tmax <= mrun0 + 8.0f)) {
                float mnew = fmaxf(mrun0, tmax);
                float corr = exp2f(mrun0 - mnew);
                mrun0 = mnew;
                #pragma unroll
                for (int it = 0; it < 8; ++it)
                    #pragma unroll
                    for (int r = 0; r < 4; ++r) yacc0[it][r] *= corr;
                #pragma unroll
                for (int r = 0; r < 4; ++r) lacc0[r] *= corr;
            }
            #pragma unroll
            for (int mt = 0; mt < 4; ++mt) {
                unsigned int ua = cvt2h(exp2f(s0[mt][0] - mrun0), exp2f(s0[mt][1] - mrun0));
                unsigned int ub = cvt2h(exp2f(s0[mt][2] - mrun0), exp2f(s0[mt][3] - mrun0));
                if (mt < 2) { pb00.u[mt * 2] = ua; pb00.u[mt * 2 + 1] = ub; }
                else        { pb01.u[(mt - 2) * 2] = ua; pb01.u[(mt - 2) * 2 + 1] = ub; }
            }
        }
        // ---- softmax q-group 1 ----
        {
            float t0 = M3(s1[0][0], s1[0][1], s1[0][2]);
            float t1 = M3(s1[0][3], s1[1][0], s1[1][1]);
            float t2 = M3(s1[1][2], s1[1][3], s1[2][0]);
            float t3 = M3(s1[2][1], s1[2][2], s1[2][3]);
            float t4 = M3(s1[3][0], s1[3][1], s1[3][2]);
            float tmax = fmaxf(M3(t0, t1, t2), M3(t3, t4, s1[3][3]));
            tmax = fmaxf(tmax, __shfl_xor(tmax, 16));
            tmax = fmaxf(tmax, __shfl_xor(tmax, 32));
            if (!__all(tmax <= mrun1 + 8.0f)) {
                float mnew = fmaxf(mrun1, tmax);
                float corr = exp2f(mrun1 - mnew);
                mrun1 = mnew;
                #pragma unroll
                for (int it = 0; it < 8; ++it)
                    #pragma unroll
                    for (int r = 0; r < 4; ++r) yacc1[it][r] *= corr;
                #pragma unroll
                for (int r = 0; r < 4; ++r) lacc1[r] *= corr;
            }
            #pragma unroll
            for (int mt = 0; mt < 4; ++mt) {
                unsigned int ua = cvt2h(exp2f(s1[mt][0] - mrun1), exp2f(s1[mt][1] - mrun1));
                unsigned int ub = cvt2h(exp2f(s1[mt][2] - mrun1), exp2f(s1[mt][3] - mrun1));
                if (mt < 2) { pb10.u[mt * 2] = ua; pb10.u[mt * 2 + 1] = ub; }
                else        { pb11.u[(mt - 2) * 2] = ua; pb11.u[(mt - 2) * 2 + 1] = ub; }
            }
        }

        // write next V tile (different buffer than vsb; completes before next barrier)
        if (more) {
            uint2 lo, hi;
            lo.x = v0.x; lo.y = v0.y; hi.x = v0.z; hi.y = v0.w;
            *(uint2*)((char*)vw + (vrow) * 128 + (vc0 ^ vsw)) = lo;
            *(uint2*)((char*)vw + (vrow) * 128 + ((vc0 + 16) ^ vsw)) = hi;
            lo.x = v1.x; lo.y = v1.y; hi.x = v1.z; hi.y = v1.w;
            *(uint2*)((char*)vw + (32 + vrow) * 128 + (vc0 ^ vsw)) = lo;
            *(uint2*)((char*)vw + (32 + vrow) * 128 + ((vc0 + 16) ^ vsw)) = hi;
            lo.x = v2.x; lo.y = v2.y; hi.x = v2.z; hi.y = v2.w;
            *(uint2*)((char*)vw + (64 + vrow) * 128 + (vc0 ^ vsw)) = lo;
            *(uint2*)((char*)vw + (64 + vrow) * 128 + ((vc0 + 16) ^ vsw)) = hi;
            lo.x = v3.x; lo.y = v3.y; hi.x = v3.z; hi.y = v3.w;
            *(uint2*)((char*)vw + (96 + vrow) * 128 + (vc0 ^ vsw)) = lo;
            *(uint2*)((char*)vw + (96 + vrow) * 128 + ((vc0 + 16) ^ vsw)) = hi;
        }

        // ---- Y^T += V^T P^T; l via ones-row MFMA ----
        __builtin_amdgcn_s_setprio(1);
        lacc0 = __builtin_amdgcn_mfma_f32_16x16x32_f16(onesv, pb00.v, lacc0, 0, 0, 0);
        lacc0 = __builtin_amdgcn_mfma_f32_16x16x32_f16(onesv, pb01.v, lacc0, 0, 0, 0);
        lacc1 = __builtin_amdgcn_mfma_f32_16x16x32_f16(onesv, pb10.v, lacc1, 0, 0, 0);
        lacc1 = __builtin_amdgcn_mfma_f32_16x16x32_f16(onesv, pb11.v, lacc1, 0, 0, 0);
        #pragma unroll
        for (int it = 0; it < 8; ++it) {
            int row = it * 16 + cl;
            f16x8 vf0 = *(const f16x8*)((const char*)vsb + row * 128 + ((g ^ (row & 7)) << 4));
            f16x8 vf1 = *(const f16x8*)((const char*)vsb + row * 128 + (((4 + g) ^ (row & 7)) << 4));
            yacc0[it] = __builtin_amdgcn_mfma_f32_16x16x32_f16(vf0, pb00.v, yacc0[it], 0, 0, 0);
            yacc0[it] = __builtin_amdgcn_mfma_f32_16x16x32_f16(vf1, pb01.v, yacc0[it], 0, 0, 0);
            yacc1[it] = __builtin_amdgcn_mfma_f32_16x16x32_f16(vf0, pb10.v, yacc1[it], 0, 0, 0);
            yacc1[it] = __builtin_amdgcn_mfma_f32_16x16x32_f16(vf1, pb11.v, yacc1[it], 0, 0, 0);
        }
        __builtin_amdgcn_s_setprio(0);
    }

    __syncthreads();   // all waves done; Ks reusable as scratch

    unsigned short* ys = &Ks[0][w * 2048];   // [16 q][128 i], 256B rows, swz
    size_t rowbase0 = (size_t)((sp * BB + b) * NN + qr0 + w * 32);
    int prow = l >> 2;
    {
        float rl = 1.0f / lacc0[0];
        #pragma unroll
        for (int it = 0; it < 8; ++it)
            #pragma unroll
            for (int r = 0; r < 4; r += 2) {
                int i = it * 16 + 4 * g + r;
                *(unsigned int*)((char*)ys + cl * 256 + ((i * 2) ^ ((cl & 7) << 4))) =
                    pack2h(yacc0[it][r] * rl, yacc0[it][r + 1] * rl);
            }
        #pragma unroll
        for (int c = 0; c < 4; ++c) {
            int seg = c * 4 + (l & 3);
            uint4 q = *(const uint4*)((const char*)ys + prow * 256 + ((seg << 4) ^ ((prow & 7) << 4)));
            *(uint4*)(Yp + (rowbase0 + prow) * II + seg * 8) = q;
        }
    }
    {
        float rl = 1.0f / lacc1[0];
        #pragma unroll
        for (int it = 0; it < 8; ++it)
            #pragma unroll
            for (int r = 0; r < 4; r += 2) {
                int i = it * 16 + 4 * g + r;
                *(unsigned int*)((char*)ys + cl * 256 + ((i * 2) ^ ((cl & 7) << 4))) =
                    pack2h(yacc1[it][r] * rl, yacc1[it][r + 1] * rl);
            }
        #pragma unroll
        for (int c = 0; c < 4; ++c) {
            int seg = c * 4 + (l & 3);
            uint4 q = *(const uint4*)((const char*)ys + prow * 256 + ((seg << 4) ^ ((prow & 7) << 4)));
            *(uint4*)(Yp + (rowbase0 + 16 + prow) * II + seg * 8) = q;
        }
    }
    if (l < 16) {
        float2 v; v.x = mrun0; v.y = lacc0[0];
        ML[rowbase0 + l] = v;
    } else if (l < 32) {
        float2 v; v.x = mrun1; v.y = lacc1[0];
        ML[rowbase0 + 16 + (l - 16)] = v;
    }
}

// ---------------- combine partials + output conv + bias + residual ----------------
// grid (NN/16, BB) = 1024 blocks = 4/CU. All 4 waves redundantly merge the block's 16 q-rows
// (Yp is L2/L3-hot); wave w owns ct in [w*4, w*4+4). Same-wave LDS park, no barriers.
__global__ __launch_bounds__(256) void combine_kernel(
    const unsigned short* __restrict__ Yp, const float2* __restrict__ ML,
    const unsigned short* __restrict__ Wo, const float* __restrict__ b_out,
    const float* __restrict__ x, float* __restrict__ out)
{
    __shared__ unsigned short Ys[4][16 * 128];

    int tid = threadIdx.x;
    int w = tid >> 6, l = tid & 63, g = l >> 4, cl = l & 15;
    int qt = blockIdx.x, b = blockIdx.y;
    int n = qt * 16 + cl;
    int ct0 = w * 4;

    float ms[NSPLIT], ls[NSPLIT], wgt[NSPLIT];
    float M = -1e30f;
    #pragma unroll
    for (int s = 0; s < NSPLIT; ++s) {
        float2 ml = ML[(size_t)(s * BB + b) * NN + n];
        ms[s] = ml.x; ls[s] = ml.y;
        M = fmaxf(M, ml.x);
    }
    float wsum = 0.f;
    #pragma unroll
    for (int s = 0; s < NSPLIT; ++s) { wgt[s] = exp2f(ms[s] - M) * ls[s]; wsum += wgt[s]; }
    float rd = 1.0f / wsum;
    #pragma unroll
    for (int s = 0; s < NSPLIT; ++s) wgt[s] *= rd;

    unsigned short* ys = Ys[w];
    #pragma unroll
    for (int j = 0; j < 4; ++j) {
        float acc[8];
        #pragma unroll
        for (int e = 0; e < 8; ++e) acc[e] = 0.f;
        #pragma unroll
        for (int s = 0; s < NSPLIT; ++s) {
            union { unsigned short s16[8]; uint4 q; } a;
            a.q = *(const uint4*)(Yp + ((size_t)(s * BB + b) * NN + n) * II + g * 32 + j * 8);
            #pragma unroll
            for (int e = 0; e < 8; ++e) acc[e] += wgt[s] * h2f(a.s16[e]);
        }
        union { unsigned int u[4]; uint4 q; } o;
        #pragma unroll
        for (int e = 0; e < 4; ++e) o.u[e] = pack2h(acc[e * 2], acc[e * 2 + 1]);
        *(uint4*)((char*)ys + cl * 256 + (((g * 4 + j) ^ (cl & 7)) << 4)) = o.q;
    }
    // same-wave write->read; no barrier needed

    f32x4 zero4 = {0.f, 0.f, 0.f, 0.f};
    f16x8 yf[4];
    #pragma unroll
    for (int kc = 0; kc < 4; ++kc)
        yf[kc] = *(const f16x8*)((const char*)ys + cl * 256 + (((kc * 4 + g) ^ (cl & 7)) << 4));
    #pragma unroll
    for (int ct = ct0; ct < ct0 + 4; ++ct) {
        f32x4 oa = zero4;
        #pragma unroll
        for (int kc = 0; kc < 4; ++kc) {
            f16x8 wf = *(const f16x8*)(Wo + (ct * 16 + cl) * II + kc * 32 + g * 8);
            oa = __builtin_amdgcn_mfma_f32_16x16x32_f16(wf, yf[kc], oa, 0, 0, 0);
        }
        #pragma unroll
        for (int r = 0; r < 4; ++r) {
            int c = ct * 16 + 4 * g + r;
            size_t off = (size_t)(b * CC + c) * NN + n;
            out[off] = oa[r] + b_out[c] + x[off];
        }
    }
}

extern "C" void kernel_launch(void* const* d_in, const int* in_sizes, int n_in,
                              void* d_out, int out_size, void* d_ws, size_t ws_size,
                              hipStream_t stream) {
    const float* x     = (const float*)d_in[0];
    const float* w_g   = (const float*)d_in[1];
    const float* b_g   = (const float*)d_in[2];
    const float* w_th  = (const float*)d_in[3];
    const float* b_th  = (const float*)d_in[4];
    const float* w_ph  = (const float*)d_in[5];
    const float* b_ph  = (const float*)d_in[6];
    const float* w_out = (const float*)d_in[7];
    const float* b_o   = (const float*)d_in[8];
    float* out = (float*)d_out;

    const size_t SZ = (size_t)BB * NN * II;
    unsigned short* Qb = (unsigned short*)d_ws;
    unsigned short* Kb = Qb + SZ;
    unsigned short* Vt = Kb + SZ;
    unsigned short* Wo = Vt + SZ;
    unsigned short* Yp = Wo + (size_t)CC * II;                 // NSPLIT * SZ fp16
    float2*         ML = (float2*)(Yp + (size_t)NSPLIT * SZ);  // NSPLIT*B*N float2

    proj_kernel<<<dim3(NN / 32, BB), dim3(256), 0, stream>>>(
        x, w_th, b_th, w_ph, b_ph, w_g, b_g, w_out, Qb, Kb, Vt, Wo);
    attn_kernel<<<dim3(NSPLIT * BB * (NN / 128)), dim3(256), 0, stream>>>(
        Qb, Kb, Vt, Yp, ML);
    combine_kernel<<<dim3(NN / 16, BB), dim3(256), 0, stream>>>(Yp, ML, Wo, b_o, x, out);
}

// Round 16
// 91.745 us; speedup vs baseline: 1.0345x; 1.0345x over previous
//
#include <hip/hip_runtime.h>

#define BB 4
#define CC 256
#define NN 4096
#define II 128
#define NSPLIT 4
#define KVH (NN / NSPLIT)   // 1024 KV rows per split
#define NT (KVH / 64)       // 16 tiles per split
#define LOG2E 1.4426950408889634f

typedef float f32x4 __attribute__((ext_vector_type(4)));
typedef _Float16 f16x8 __attribute__((ext_vector_type(8)));

static __device__ __forceinline__ unsigned short f2h(float f) {
    _Float16 h = (_Float16)f;
    return __builtin_bit_cast(unsigned short, h);
}
static __device__ __forceinline__ float h2f(unsigned short s) {
    return (float)__builtin_bit_cast(_Float16, s);
}
static __device__ __forceinline__ unsigned int pack2h(float a, float b) {
    return (unsigned int)f2h(a) | ((unsigned int)f2h(b) << 16);
}
static __device__ __forceinline__ unsigned int cvt2h(float a, float b) {
    return __builtin_bit_cast(unsigned int, __builtin_amdgcn_cvt_pkrtz(a, b));
}
#define M3(a, b, c) fmaxf(fmaxf((a), (b)), (c))

// ---------------- MFMA projection: one (mat, batch, 64-n strip) per block (R13) ----------------
__global__ __launch_bounds__(256) void proj_kernel(
    const float* __restrict__ x,
    const float* __restrict__ w_th, const float* __restrict__ b_th,
    const float* __restrict__ w_ph, const float* __restrict__ b_ph,
    const float* __restrict__ w_g,  const float* __restrict__ b_g,
    const float* __restrict__ w_out,
    unsigned short* __restrict__ Qb, unsigned short* __restrict__ Kb,
    unsigned short* __restrict__ Vt, unsigned short* __restrict__ Wo)
{
    __shared__ char lds[24576];
    unsigned short* wl = (unsigned short*)lds;            // [128 i][64 c] fp16, 128B rows, swz
    unsigned short* xl = (unsigned short*)(lds + 16384);  // [64 n][64 c]  fp16, 128B rows, swz

    int tid = threadIdx.x;
    int w = tid >> 6, l = tid & 63, g = l >> 4, cl = l & 15;
    int mat = blockIdx.z, b = blockIdx.y, n0 = blockIdx.x * 64;
    const float* wp = (mat == 0) ? w_th : (mat == 1) ? w_ph : w_g;
    const float* bp = (mat == 0) ? b_th : (mat == 1) ? b_ph : b_g;

    f32x4 acc[2][4];
    #pragma unroll
    for (int it = 0; it < 2; ++it)
        #pragma unroll
        for (int nt = 0; nt < 4; ++nt) acc[it][nt] = (f32x4){0.f, 0.f, 0.f, 0.f};

    const float* xb = x + (size_t)b * CC * NN;
    int c2 = tid >> 3, nch = tid & 7;

    for (int c0 = 0; c0 < CC; c0 += 64) {
        __syncthreads();
        #pragma unroll
        for (int r = 0; r < 4; ++r) {
            int idx = r * 256 + tid;
            int row = idx >> 3, ch = idx & 7;
            const float* src = wp + row * CC + c0 + ch * 8;
            float4 a = *(const float4*)src;
            float4 bq = *(const float4*)(src + 4);
            union { unsigned int u[4]; uint4 q; } pk;
            pk.u[0] = pack2h(a.x, a.y);  pk.u[1] = pack2h(a.z, a.w);
            pk.u[2] = pack2h(bq.x, bq.y); pk.u[3] = pack2h(bq.z, bq.w);
            *(uint4*)((char*)wl + row * 128 + ((ch ^ (row & 7)) << 4)) = pk.q;
        }
        {
            const float* xsrc = xb + (size_t)(c0 + c2 * 2) * NN + n0 + nch * 8;
            float4 x00 = *(const float4*)xsrc;
            float4 x01 = *(const float4*)(xsrc + 4);
            float4 x10 = *(const float4*)(xsrc + NN);
            float4 x11 = *(const float4*)(xsrc + NN + 4);
            float lo[8] = {x00.x, x00.y, x00.z, x00.w, x01.x, x01.y, x01.z, x01.w};
            float hi[8] = {x10.x, x10.y, x10.z, x10.w, x11.x, x11.y, x11.z, x11.w};
            #pragma unroll
            for (int t = 0; t < 8; ++t) {
                int n = nch * 8 + t;
                *(unsigned int*)((char*)xl + n * 128 + ((c2 * 4) ^ ((n & 7) << 4))) = pack2h(lo[t], hi[t]);
            }
        }
        __syncthreads();
        #pragma unroll
        for (int kc = 0; kc < 2; ++kc) {
            f16x8 af[2], bf[4];
            #pragma unroll
            for (int it = 0; it < 2; ++it) {
                int row = w * 32 + it * 16 + cl;
                af[it] = *(const f16x8*)((const char*)wl + row * 128 + (((kc * 4 + g) ^ (row & 7)) << 4));
            }
            #pragma unroll
            for (int nt = 0; nt < 4; ++nt) {
                int row = nt * 16 + cl;
                bf[nt] = *(const f16x8*)((const char*)xl + row * 128 + (((kc * 4 + g) ^ (row & 7)) << 4));
            }
            #pragma unroll
            for (int it = 0; it < 2; ++it)
                #pragma unroll
                for (int nt = 0; nt < 4; ++nt)
                    acc[it][nt] = __builtin_amdgcn_mfma_f32_16x16x32_f16(af[it], bf[nt], acc[it][nt], 0, 0, 0);
        }
    }

    float bv[2][4];
    #pragma unroll
    for (int it = 0; it < 2; ++it)
        #pragma unroll
        for (int r = 0; r < 4; ++r) bv[it][r] = bp[w * 32 + it * 16 + 4 * g + r];
    float scale = (mat == 0) ? LOG2E : 1.0f;

    __syncthreads();
    if (mat < 2) {
        unsigned short* pk = (unsigned short*)lds;
        #pragma unroll
        for (int it = 0; it < 2; ++it)
            #pragma unroll
            for (int nt = 0; nt < 4; ++nt)
                #pragma unroll
                for (int r = 0; r < 4; r += 2) {
                    int n = nt * 16 + cl;
                    int i = w * 32 + it * 16 + 4 * g + r;
                    unsigned int v = pack2h((acc[it][nt][r] + bv[it][r]) * scale,
                                            (acc[it][nt][r + 1] + bv[it][r + 1]) * scale);
                    *(unsigned int*)((char*)pk + n * 256 + ((i * 2) ^ ((n & 7) << 4))) = v;
                }
        __syncthreads();
        unsigned short* out = (mat == 0) ? Qb : Kb;
        #pragma unroll
        for (int r = 0; r < 4; ++r) {
            int idx = r * 256 + tid;
            int n = idx >> 4, seg = idx & 15;
            uint4 q = *(const uint4*)((const char*)pk + n * 256 + ((seg << 4) ^ ((n & 7) << 4)));
            *(uint4*)(out + (size_t)(b * NN + n0 + n) * II + seg * 8) = q;
        }
    } else {
        unsigned short* pk = (unsigned short*)lds;
        #pragma unroll
        for (int it = 0; it < 2; ++it)
            #pragma unroll
            for (int nt = 0; nt < 4; ++nt)
                #pragma unroll
                for (int r = 0; r < 4; ++r) {
                    int i = w * 32 + it * 16 + 4 * g + r;
                    int n = nt * 16 + cl;
                    *(unsigned short*)((char*)pk + i * 128 + ((n * 2) ^ ((i & 7) << 4))) =
                        f2h(acc[it][nt][r] + bv[it][r]);
                }
        __syncthreads();
        #pragma unroll
        for (int r = 0; r < 4; ++r) {
            int idx = r * 256 + tid;
            int i = idx >> 3, seg = idx & 7;
            uint4 q = *(const uint4*)((const char*)pk + i * 128 + ((seg << 4) ^ ((i & 7) << 4)));
            *(uint4*)(Vt + (size_t)(b * II + i) * NN + n0 + seg * 8) = q;
        }
        if (blockIdx.x == 0) {
            #pragma unroll
            for (int r = 0; r < 16; ++r) {
                int idx = (r * 256 + tid) * 8;
                float4 a = *(const float4*)(w_out + idx);
                float4 b4 = *(const float4*)(w_out + idx + 4);
                union { unsigned int u[4]; uint4 q; } pw;
                pw.u[0] = pack2h(a.x, a.y);   pw.u[1] = pack2h(a.z, a.w);
                pw.u[2] = pack2h(b4.x, b4.y); pw.u[3] = pack2h(b4.z, b4.w);
                *(uint4*)&Wo[idx] = pw.q;
            }
        }
    }
}

// ---------------- flash attention: 8 waves / 512 threads, K/V staged ONCE per 256 q ----------------
// grid 256 (= 1 block/CU): comb = (id&7)*2 + ((id>>3)&1): b=comb>>2, sp=comb&3; qt=id>>4.
// Merges the two former qt-blocks that staged identical K/V -> staging traffic halved.
__global__ __launch_bounds__(512, 1) void attn_kernel(
    const unsigned short* __restrict__ Qb,   // [B][N][II] fp16 (pre-scaled by log2e)
    const unsigned short* __restrict__ Kb,   // [B][N][II] fp16
    const unsigned short* __restrict__ Vb,   // [B][II][N] fp16
    unsigned short* __restrict__ Yp,         // [NSPLIT][B][N][II] fp16 normalized partial
    float2* __restrict__ ML)                 // [NSPLIT][B][N] {m,l} (base-2 domain)
{
    __shared__ unsigned short Ks[2][64 * 128];   // dbuf K (32 KB)
    __shared__ unsigned short Vs[2][128 * 64];   // dbuf V^T, permuted cols (32 KB)

    int tid = threadIdx.x;
    int w = tid >> 6, l = tid & 63, g = l >> 4, cl = l & 15;
    int id = blockIdx.x;
    int comb = (id & 7) * 2 + ((id >> 3) & 1);
    int b = comb >> 2, sp = comb & 3, qt = id >> 4;
    int qr0 = qt * 256;
    int m_base = sp * KVH;

    f16x8 qa0[4], qa1[4];
    {
        const unsigned short* qrow0 = Qb + (size_t)(b * NN + qr0 + w * 32 + cl) * II;
        const unsigned short* qrow1 = qrow0 + 16 * II;
        #pragma unroll
        for (int kc = 0; kc < 4; ++kc) {
            qa0[kc] = *(const f16x8*)(qrow0 + kc * 32 + g * 8);
            qa1[kc] = *(const f16x8*)(qrow1 + kc * 32 + g * 8);
        }
    }
    const f16x8 onesv = {(_Float16)1.f, (_Float16)1.f, (_Float16)1.f, (_Float16)1.f,
                         (_Float16)1.f, (_Float16)1.f, (_Float16)1.f, (_Float16)1.f};

    f32x4 yacc0[8], yacc1[8], lacc0, lacc1;
    #pragma unroll
    for (int it = 0; it < 8; ++it) {
        yacc0[it] = (f32x4){0.f, 0.f, 0.f, 0.f};
        yacc1[it] = (f32x4){0.f, 0.f, 0.f, 0.f};
    }
    lacc0 = (f32x4){0.f, 0.f, 0.f, 0.f};
    lacc1 = (f32x4){0.f, 0.f, 0.f, 0.f};
    float mrun0 = -1e30f, mrun1 = -1e30f;

    const unsigned short* kb = Kb + (size_t)(b * NN + m_base) * II;
    const unsigned short* vb = Vb + (size_t)b * II * NN + m_base;
    // 512-thread staging: K rows {krow, 32+krow}, V rows {vrow, 64+vrow}
    int krow = tid >> 4, kch = tid & 15;     // krow 0..31
    int vrow = tid >> 3, vch = tid & 7;      // vrow 0..63
    int kswz = (kch ^ (krow & 7)) << 4;      // (32+krow)&7 == krow&7 -> same swizzle
    int vsw = (vrow & 7) << 4;
    int vc0 = ((vch >> 2) * 32 + (vch & 1) * 16 + ((vch >> 1) & 1) * 4) * 2;

    uint4 k0, k1, v0, v1;   // named regs (no PromoteAlloca); half of the 256-thread version
    k0 = *(const uint4*)(kb + (size_t)(krow) * II + kch * 8);
    k1 = *(const uint4*)(kb + (size_t)(32 + krow) * II + kch * 8);
    v0 = *(const uint4*)(vb + (size_t)(vrow) * NN + vch * 8);
    v1 = *(const uint4*)(vb + (size_t)(64 + vrow) * NN + vch * 8);
    // publish tile 0 into buf 0 (visible after first barrier)
    {
        *(uint4*)((char*)Ks[0] + (krow) * 256 + kswz) = k0;
        *(uint4*)((char*)Ks[0] + (32 + krow) * 256 + kswz) = k1;
        uint2 lo, hi;
        lo.x = v0.x; lo.y = v0.y; hi.x = v0.z; hi.y = v0.w;
        *(uint2*)((char*)Vs[0] + (vrow) * 128 + (vc0 ^ vsw)) = lo;
        *(uint2*)((char*)Vs[0] + (vrow) * 128 + ((vc0 + 16) ^ vsw)) = hi;
        lo.x = v1.x; lo.y = v1.y; hi.x = v1.z; hi.y = v1.w;
        *(uint2*)((char*)Vs[0] + (64 + vrow) * 128 + (vc0 ^ vsw)) = lo;
        *(uint2*)((char*)Vs[0] + (64 + vrow) * 128 + ((vc0 + 16) ^ vsw)) = hi;
    }

    for (int t = 0; t < NT; ++t) {
        __syncthreads();   // buf[t&1] writes visible; all waves finished iter t-1
        const unsigned short* ksb = Ks[t & 1];
        const unsigned short* vsb = Vs[t & 1];
        unsigned short* kw = Ks[(t + 1) & 1];
        unsigned short* vw = Vs[(t + 1) & 1];
        bool more = (t + 1 < NT);
        if (more) {   // issue next tile's loads; latency hides under QK/softmax
            const unsigned short* kp = kb + (size_t)(t + 1) * 64 * II;
            const unsigned short* vp = vb + (size_t)(t + 1) * 64;
            k0 = *(const uint4*)(kp + (size_t)(krow) * II + kch * 8);
            k1 = *(const uint4*)(kp + (size_t)(32 + krow) * II + kch * 8);
            v0 = *(const uint4*)(vp + (size_t)(vrow) * NN + vch * 8);
            v1 = *(const uint4*)(vp + (size_t)(64 + vrow) * NN + vch * 8);
        }

        // ---- S^T = K Q^T for both q-groups, each K fragment read ONCE ----
        f32x4 s0[4], s1[4];
        #pragma unroll
        for (int mt = 0; mt < 4; ++mt) {
            s0[mt] = (f32x4){0.f, 0.f, 0.f, 0.f};
            s1[mt] = (f32x4){0.f, 0.f, 0.f, 0.f};
        }
        __builtin_amdgcn_s_setprio(1);
        #pragma unroll
        for (int mt = 0; mt < 4; ++mt) {
            int row = mt * 16 + cl;
            #pragma unroll
            for (int kc = 0; kc < 4; ++kc) {
                f16x8 kf = *(const f16x8*)((const char*)ksb + row * 256 + (((kc * 4 + g) ^ (row & 7)) << 4));
                s0[mt] = __builtin_amdgcn_mfma_f32_16x16x32_f16(kf, qa0[kc], s0[mt], 0, 0, 0);
                s1[mt] = __builtin_amdgcn_mfma_f32_16x16x32_f16(kf, qa1[kc], s1[mt], 0, 0, 0);
            }
        }
        __builtin_amdgcn_s_setprio(0);

        // write next K tile mid-stream (K regs die; different buffer than ksb)
        if (more) {
            *(uint4*)((char*)kw + (krow) * 256 + kswz) = k0;
            *(uint4*)((char*)kw + (32 + krow) * 256 + kswz) = k1;
        }

        // ---- softmax q-group 0 ----
        union { unsigned int u[4]; f16x8 v; } pb00, pb01, pb10, pb11;
        {
            float t0 = M3(s0[0][0], s0[0][1], s0[0][2]);
            float t1 = M3(s0[0][3], s0[1][0], s0[1][1]);
            float t2 = M3(s0[1][2], s0[1][3], s0[2][0]);
            float t3 = M3(s0[2][1], s0[2][2], s0[2][3]);
            float t4 = M3(s0[3][0], s0[3][1], s0[3][2]);
            float tmax = fmaxf(M3(t0, t1, t2), M3(t3, t4, s0[3][3]));
            tmax = fmaxf(tmax, __shfl_xor(tmax, 16));
            tmax = fmaxf(tmax, __shfl_xor(tmax, 32));
            if (!__all(tmax <= mrun0 + 8.0f)) {
                float mnew = fmaxf(mrun0, tmax);
                float corr = exp2f(mrun0 - mnew);
                mrun0 = mnew;
                #pragma unroll
                for (int it = 0; it < 8; ++it)
                    #pragma unroll
                    for (int r = 0; r < 4; ++r) yacc0[it][r] *= corr;
                #pragma unroll
                for (int r = 0; r < 4; ++r) lacc0[r] *= corr;
            }
            #pragma unroll
            for (int mt = 0; mt < 4; ++mt) {
                unsigned int ua = cvt2h(exp2f(s0[mt][0] - mrun0), exp2f(s0[mt][1] - mrun0));
                unsigned int ub = cvt2h(exp2f(s0[mt][2] - mrun0), exp2f(s0[mt][3] - mrun0));
                if (mt < 2) { pb00.u[mt * 2] = ua; pb00.u[mt * 2 + 1] = ub; }
                else        { pb01.u[(mt - 2) * 2] = ua; pb01.u[(mt - 2) * 2 + 1] = ub; }
            }
        }
        // ---- softmax q-group 1 ----
        {
            float t0 = M3(s1[0][0], s1[0][1], s1[0][2]);
            float t1 = M3(s1[0][3], s1[1][0], s1[1][1]);
            float t2 = M3(s1[1][2], s1[1][3], s1[2][0]);
            float t3 = M3(s1[2][1], s1[2][2], s1[2][3]);
            float t4 = M3(s1[3][0], s1[3][1], s1[3][2]);
            float tmax = fmaxf(M3(t0, t1, t2), M3(t3, t4, s1[3][3]));
            tmax = fmaxf(tmax, __shfl_xor(tmax, 16));
            tmax = fmaxf(tmax, __shfl_xor(tmax, 32));
            if (!__all(tmax <= mrun1 + 8.0f)) {
                float mnew = fmaxf(mrun1, tmax);
                float corr = exp2f(mrun1 - mnew);
                mrun1 = mnew;
                #pragma unroll
                for (int it = 0; it < 8; ++it)
                    #pragma unroll
                    for (int r = 0; r < 4; ++r) yacc1[it][r] *= corr;
                #pragma unroll
                for (int r = 0; r < 4; ++r) lacc1[r] *= corr;
            }
            #pragma unroll
            for (int mt = 0; mt < 4; ++mt) {
                unsigned int ua = cvt2h(exp2f(s1[mt][0] - mrun1), exp2f(s1[mt][1] - mrun1));
                unsigned int ub = cvt2h(exp2f(s1[mt][2] - mrun1), exp2f(s1[mt][3] - mrun1));
                if (mt < 2) { pb10.u[mt * 2] = ua; pb10.u[mt * 2 + 1] = ub; }
                else        { pb11.u[(mt - 2) * 2] = ua; pb11.u[(mt - 2) * 2 + 1] = ub; }
            }
        }

        // write next V tile (different buffer than vsb; completes before next barrier)
        if (more) {
            uint2 lo, hi;
            lo.x = v0.x; lo.y = v0.y; hi.x = v0.z; hi.y = v0.w;
            *(uint2*)((char*)vw + (vrow) * 128 + (vc0 ^ vsw)) = lo;
            *(uint2*)((char*)vw + (vrow) * 128 + ((vc0 + 16) ^ vsw)) = hi;
            lo.x = v1.x; lo.y = v1.y; hi.x = v1.z; hi.y = v1.w;
            *(uint2*)((char*)vw + (64 + vrow) * 128 + (vc0 ^ vsw)) = lo;
            *(uint2*)((char*)vw + (64 + vrow) * 128 + ((vc0 + 16) ^ vsw)) = hi;
        }

        // ---- Y^T += V^T P^T; l via ones-row MFMA ----
        __builtin_amdgcn_s_setprio(1);
        lacc0 = __builtin_amdgcn_mfma_f32_16x16x32_f16(onesv, pb00.v, lacc0, 0, 0, 0);
        lacc0 = __builtin_amdgcn_mfma_f32_16x16x32_f16(onesv, pb01.v, lacc0, 0, 0, 0);
        lacc1 = __builtin_amdgcn_mfma_f32_16x16x32_f16(onesv, pb10.v, lacc1, 0, 0, 0);
        lacc1 = __builtin_amdgcn_mfma_f32_16x16x32_f16(onesv, pb11.v, lacc1, 0, 0, 0);
        #pragma unroll
        for (int it = 0; it < 8; ++it) {
            int row = it * 16 + cl;
            f16x8 vf0 = *(const f16x8*)((const char*)vsb + row * 128 + ((g ^ (row & 7)) << 4));
            f16x8 vf1 = *(const f16x8*)((const char*)vsb + row * 128 + (((4 + g) ^ (row & 7)) << 4));
            yacc0[it] = __builtin_amdgcn_mfma_f32_16x16x32_f16(vf0, pb00.v, yacc0[it], 0, 0, 0);
            yacc0[it] = __builtin_amdgcn_mfma_f32_16x16x32_f16(vf1, pb01.v, yacc0[it], 0, 0, 0);
            yacc1[it] = __builtin_amdgcn_mfma_f32_16x16x32_f16(vf0, pb10.v, yacc1[it], 0, 0, 0);
            yacc1[it] = __builtin_amdgcn_mfma_f32_16x16x32_f16(vf1, pb11.v, yacc1[it], 0, 0, 0);
        }
        __builtin_amdgcn_s_setprio(0);
    }

    __syncthreads();   // all waves done; Ks reusable as scratch

    unsigned short* ys = &Ks[0][w * 2048];   // 8 waves x 4KB = 32KB = Ks[0]+Ks[1]
    size_t rowbase0 = (size_t)((sp * BB + b) * NN + qr0 + w * 32);
    int prow = l >> 2;
    {
        float rl = 1.0f / lacc0[0];
        #pragma unroll
        for (int it = 0; it < 8; ++it)
            #pragma unroll
            for (int r = 0; r < 4; r += 2) {
                int i = it * 16 + 4 * g + r;
                *(unsigned int*)((char*)ys + cl * 256 + ((i * 2) ^ ((cl & 7) << 4))) =
                    pack2h(yacc0[it][r] * rl, yacc0[it][r + 1] * rl);
            }
        #pragma unroll
        for (int c = 0; c < 4; ++c) {
            int seg = c * 4 + (l & 3);
            uint4 q = *(const uint4*)((const char*)ys + prow * 256 + ((seg << 4) ^ ((prow & 7) << 4)));
            *(uint4*)(Yp + (rowbase0 + prow) * II + seg * 8) = q;
        }
    }
    {
        float rl = 1.0f / lacc1[0];
        #pragma unroll
        for (int it = 0; it < 8; ++it)
            #pragma unroll
            for (int r = 0; r < 4; r += 2) {
                int i = it * 16 + 4 * g + r;
                *(unsigned int*)((char*)ys + cl * 256 + ((i * 2) ^ ((cl & 7) << 4))) =
                    pack2h(yacc1[it][r] * rl, yacc1[it][r + 1] * rl);
            }
        #pragma unroll
        for (int c = 0; c < 4; ++c) {
            int seg = c * 4 + (l & 3);
            uint4 q = *(const uint4*)((const char*)ys + prow * 256 + ((seg << 4) ^ ((prow & 7) << 4)));
            *(uint4*)(Yp + (rowbase0 + 16 + prow) * II + seg * 8) = q;
        }
    }
    if (l < 16) {
        float2 v; v.x = mrun0; v.y = lacc0[0];
        ML[rowbase0 + l] = v;
    } else if (l < 32) {
        float2 v; v.x = mrun1; v.y = lacc1[0];
        ML[rowbase0 + 16 + (l - 16)] = v;
    }
}

// ---------------- combine (R13): grid (NN/32, BB); wave: q-half = w&1, ct-half = w>>1 ----------------
__global__ __launch_bounds__(256) void combine_kernel(
    const unsigned short* __restrict__ Yp, const float2* __restrict__ ML,
    const unsigned short* __restrict__ Wo, const float* __restrict__ b_out,
    const float* __restrict__ x, float* __restrict__ out)
{
    __shared__ unsigned short Ys[4][16 * 128];

    int tid = threadIdx.x;
    int w = tid >> 6, l = tid & 63, g = l >> 4, cl = l & 15;
    int qt = blockIdx.x, b = blockIdx.y;
    int n = qt * 32 + (w & 1) * 16 + cl;
    int ct0 = (w >> 1) * 8;

    float ms[NSPLIT], ls[NSPLIT], wgt[NSPLIT];
    float M = -1e30f;
    #pragma unroll
    for (int s = 0; s < NSPLIT; ++s) {
        float2 ml = ML[(size_t)(s * BB + b) * NN + n];
        ms[s] = ml.x; ls[s] = ml.y;
        M = fmaxf(M, ml.x);
    }
    float wsum = 0.f;
    #pragma unroll
    for (int s = 0; s < NSPLIT; ++s) { wgt[s] = exp2f(ms[s] - M) * ls[s]; wsum += wgt[s]; }
    float rd = 1.0f / wsum;
    #pragma unroll
    for (int s = 0; s < NSPLIT; ++s) wgt[s] *= rd;

    unsigned short* ys = Ys[w];
    #pragma unroll
    for (int j = 0; j < 4; ++j) {
        float acc[8];
        #pragma unroll
        for (int e = 0; e < 8; ++e) acc[e] = 0.f;
        #pragma unroll
        for (int s = 0; s < NSPLIT; ++s) {
            union { unsigned short s16[8]; uint4 q; } a;
            a.q = *(const uint4*)(Yp + ((size_t)(s * BB + b) * NN + n) * II + g * 32 + j * 8);
            #pragma unroll
            for (int e = 0; e < 8; ++e) acc[e] += wgt[s] * h2f(a.s16[e]);
        }
        union { unsigned int u[4]; uint4 q; } o;
        #pragma unroll
        for (int e = 0; e < 4; ++e) o.u[e] = pack2h(acc[e * 2], acc[e * 2 + 1]);
        *(uint4*)((char*)ys + cl * 256 + (((g * 4 + j) ^ (cl & 7)) << 4)) = o.q;
    }
    // same-wave write->read; no barrier needed

    f32x4 zero4 = {0.f, 0.f, 0.f, 0.f};
    f16x8 yf[4];
    #pragma unroll
    for (int kc = 0; kc < 4; ++kc)
        yf[kc] = *(const f16x8*)((const char*)ys + cl * 256 + (((kc * 4 + g) ^ (cl & 7)) << 4));
    for (int ct = ct0; ct < ct0 + 8; ++ct) {
        f32x4 oa = zero4;
        #pragma unroll
        for (int kc = 0; kc < 4; ++kc) {
            f16x8 wf = *(const f16x8*)(Wo + (ct * 16 + cl) * II + kc * 32 + g * 8);
            oa = __builtin_amdgcn_mfma_f32_16x16x32_f16(wf, yf[kc], oa, 0, 0, 0);
        }
        #pragma unroll
        for (int r = 0; r < 4; ++r) {
            int c = ct * 16 + 4 * g + r;
            size_t off = (size_t)(b * CC + c) * NN + n;
            out[off] = oa[r] + b_out[c] + x[off];
        }
    }
}

extern "C" void kernel_launch(void* const* d_in, const int* in_sizes, int n_in,
                              void* d_out, int out_size, void* d_ws, size_t ws_size,
                              hipStream_t stream) {
    const float* x     = (const float*)d_in[0];
    const float* w_g   = (const float*)d_in[1];
    const float* b_g   = (const float*)d_in[2];
    const float* w_th  = (const float*)d_in[3];
    const float* b_th  = (const float*)d_in[4];
    const float* w_ph  = (const float*)d_in[5];
    const float* b_ph  = (const float*)d_in[6];
    const float* w_out = (const float*)d_in[7];
    const float* b_o   = (const float*)d_in[8];
    float* out = (float*)d_out;

    const size_t SZ = (size_t)BB * NN * II;
    unsigned short* Qb = (unsigned short*)d_ws;
    unsigned short* Kb = Qb + SZ;
    unsigned short* Vt = Kb + SZ;
    unsigned short* Wo = Vt + SZ;
    unsigned short* Yp = Wo + (size_t)CC * II;                 // NSPLIT * SZ fp16
    float2*         ML = (float2*)(Yp + (size_t)NSPLIT * SZ);  // NSPLIT*B*N float2

    proj_kernel<<<dim3(NN / 64, BB, 3), dim3(256), 0, stream>>>(
        x, w_th, b_th, w_ph, b_ph, w_g, b_g, w_out, Qb, Kb, Vt, Wo);
    attn_kernel<<<dim3(NSPLIT * BB * (NN / 256)), dim3(512), 0, stream>>>(
        Qb, Kb, Vt, Yp, ML);
    combine_kernel<<<dim3(NN / 32, BB), dim3(256), 0, stream>>>(Yp, ML, Wo, b_o, x, out);
}

// Round 17
// 91.645 us; speedup vs baseline: 1.0356x; 1.0011x over previous
//
#include <hip/hip_runtime.h>

#define BB 4
#define CC 256
#define NN 4096
#define II 128
#define NSPLIT 4
#define KVH (NN / NSPLIT)   // 1024 KV rows per split
#define NT (KVH / 64)       // 16 tiles per split
#define LOG2E 1.4426950408889634f

typedef float f32x4 __attribute__((ext_vector_type(4)));
typedef _Float16 f16x8 __attribute__((ext_vector_type(8)));

static __device__ __forceinline__ unsigned short f2h(float f) {
    _Float16 h = (_Float16)f;
    return __builtin_bit_cast(unsigned short, h);
}
static __device__ __forceinline__ float h2f(unsigned short s) {
    return (float)__builtin_bit_cast(_Float16, s);
}
static __device__ __forceinline__ unsigned int pack2h(float a, float b) {
    return (unsigned int)f2h(a) | ((unsigned int)f2h(b) << 16);
}
static __device__ __forceinline__ unsigned int cvt2h(float a, float b) {
    return __builtin_bit_cast(unsigned int, __builtin_amdgcn_cvt_pkrtz(a, b));
}
#define M3(a, b, c) fmaxf(fmaxf((a), (b)), (c))

// ---------------- MFMA projection: one (mat, batch, 64-n strip) per block ----------------
__global__ __launch_bounds__(256) void proj_kernel(
    const float* __restrict__ x,
    const float* __restrict__ w_th, const float* __restrict__ b_th,
    const float* __restrict__ w_ph, const float* __restrict__ b_ph,
    const float* __restrict__ w_g,  const float* __restrict__ b_g,
    const float* __restrict__ w_out,
    unsigned short* __restrict__ Qb, unsigned short* __restrict__ Kb,
    unsigned short* __restrict__ Vt, unsigned short* __restrict__ Wo)
{
    __shared__ char lds[24576];
    unsigned short* wl = (unsigned short*)lds;            // [128 i][64 c] fp16, 128B rows, swz
    unsigned short* xl = (unsigned short*)(lds + 16384);  // [64 n][64 c]  fp16, 128B rows, swz

    int tid = threadIdx.x;
    int w = tid >> 6, l = tid & 63, g = l >> 4, cl = l & 15;
    int mat = blockIdx.z, b = blockIdx.y, n0 = blockIdx.x * 64;
    const float* wp = (mat == 0) ? w_th : (mat == 1) ? w_ph : w_g;
    const float* bp = (mat == 0) ? b_th : (mat == 1) ? b_ph : b_g;

    f32x4 acc[2][4];
    #pragma unroll
    for (int it = 0; it < 2; ++it)
        #pragma unroll
        for (int nt = 0; nt < 4; ++nt) acc[it][nt] = (f32x4){0.f, 0.f, 0.f, 0.f};

    const float* xb = x + (size_t)b * CC * NN;
    int c2 = tid >> 3, nch = tid & 7;

    for (int c0 = 0; c0 < CC; c0 += 64) {
        __syncthreads();
        #pragma unroll
        for (int r = 0; r < 4; ++r) {
            int idx = r * 256 + tid;
            int row = idx >> 3, ch = idx & 7;
            const float* src = wp + row * CC + c0 + ch * 8;
            float4 a = *(const float4*)src;
            float4 bq = *(const float4*)(src + 4);
            union { unsigned int u[4]; uint4 q; } pk;
            pk.u[0] = pack2h(a.x, a.y);  pk.u[1] = pack2h(a.z, a.w);
            pk.u[2] = pack2h(bq.x, bq.y); pk.u[3] = pack2h(bq.z, bq.w);
            *(uint4*)((char*)wl + row * 128 + ((ch ^ (row & 7)) << 4)) = pk.q;
        }
        {
            const float* xsrc = xb + (size_t)(c0 + c2 * 2) * NN + n0 + nch * 8;
            float4 x00 = *(const float4*)xsrc;
            float4 x01 = *(const float4*)(xsrc + 4);
            float4 x10 = *(const float4*)(xsrc + NN);
            float4 x11 = *(const float4*)(xsrc + NN + 4);
            float lo[8] = {x00.x, x00.y, x00.z, x00.w, x01.x, x01.y, x01.z, x01.w};
            float hi[8] = {x10.x, x10.y, x10.z, x10.w, x11.x, x11.y, x11.z, x11.w};
            #pragma unroll
            for (int t = 0; t < 8; ++t) {
                int n = nch * 8 + t;
                *(unsigned int*)((char*)xl + n * 128 + ((c2 * 4) ^ ((n & 7) << 4))) = pack2h(lo[t], hi[t]);
            }
        }
        __syncthreads();
        #pragma unroll
        for (int kc = 0; kc < 2; ++kc) {
            f16x8 af[2], bf[4];
            #pragma unroll
            for (int it = 0; it < 2; ++it) {
                int row = w * 32 + it * 16 + cl;
                af[it] = *(const f16x8*)((const char*)wl + row * 128 + (((kc * 4 + g) ^ (row & 7)) << 4));
            }
            #pragma unroll
            for (int nt = 0; nt < 4; ++nt) {
                int row = nt * 16 + cl;
                bf[nt] = *(const f16x8*)((const char*)xl + row * 128 + (((kc * 4 + g) ^ (row & 7)) << 4));
            }
            #pragma unroll
            for (int it = 0; it < 2; ++it)
                #pragma unroll
                for (int nt = 0; nt < 4; ++nt)
                    acc[it][nt] = __builtin_amdgcn_mfma_f32_16x16x32_f16(af[it], bf[nt], acc[it][nt], 0, 0, 0);
        }
    }

    float bv[2][4];
    #pragma unroll
    for (int it = 0; it < 2; ++it)
        #pragma unroll
        for (int r = 0; r < 4; ++r) bv[it][r] = bp[w * 32 + it * 16 + 4 * g + r];
    float scale = (mat == 0) ? LOG2E : 1.0f;

    __syncthreads();
    if (mat < 2) {
        unsigned short* pk = (unsigned short*)lds;
        #pragma unroll
        for (int it = 0; it < 2; ++it)
            #pragma unroll
            for (int nt = 0; nt < 4; ++nt)
                #pragma unroll
                for (int r = 0; r < 4; r += 2) {
                    int n = nt * 16 + cl;
                    int i = w * 32 + it * 16 + 4 * g + r;
                    unsigned int v = pack2h((acc[it][nt][r] + bv[it][r]) * scale,
                                            (acc[it][nt][r + 1] + bv[it][r + 1]) * scale);
                    *(unsigned int*)((char*)pk + n * 256 + ((i * 2) ^ ((n & 7) << 4))) = v;
                }
        __syncthreads();
        unsigned short* out = (mat == 0) ? Qb : Kb;
        #pragma unroll
        for (int r = 0; r < 4; ++r) {
            int idx = r * 256 + tid;
            int n = idx >> 4, seg = idx & 15;
            uint4 q = *(const uint4*)((const char*)pk + n * 256 + ((seg << 4) ^ ((n & 7) << 4)));
            *(uint4*)(out + (size_t)(b * NN + n0 + n) * II + seg * 8) = q;
        }
    } else {
        unsigned short* pk = (unsigned short*)lds;
        #pragma unroll
        for (int it = 0; it < 2; ++it)
            #pragma unroll
            for (int nt = 0; nt < 4; ++nt)
                #pragma unroll
                for (int r = 0; r < 4; ++r) {
                    int i = w * 32 + it * 16 + 4 * g + r;
                    int n = nt * 16 + cl;
                    *(unsigned short*)((char*)pk + i * 128 + ((n * 2) ^ ((i & 7) << 4))) =
                        f2h(acc[it][nt][r] + bv[it][r]);
                }
        __syncthreads();
        #pragma unroll
        for (int r = 0; r < 4; ++r) {
            int idx = r * 256 + tid;
            int i = idx >> 3, seg = idx & 7;
            uint4 q = *(const uint4*)((const char*)pk + i * 128 + ((seg << 4) ^ ((i & 7) << 4)));
            *(uint4*)(Vt + (size_t)(b * II + i) * NN + n0 + seg * 8) = q;
        }
        if (blockIdx.x == 0) {
            #pragma unroll
            for (int r = 0; r < 16; ++r) {
                int idx = (r * 256 + tid) * 8;
                float4 a = *(const float4*)(w_out + idx);
                float4 b4 = *(const float4*)(w_out + idx + 4);
                union { unsigned int u[4]; uint4 q; } pw;
                pw.u[0] = pack2h(a.x, a.y);   pw.u[1] = pack2h(a.z, a.w);
                pw.u[2] = pack2h(b4.x, b4.y); pw.u[3] = pack2h(b4.z, b4.w);
                *(uint4*)&Wo[idx] = pw.q;
            }
        }
    }
}

// ---------------- flash attention: 8 waves / 512 threads; PV(g0) overlapped with softmax(g1) ----------------
// grid 256 (1 block/CU): comb = (id&7)*2 + ((id>>3)&1): b=comb>>2, sp=comb&3; qt=id>>4.
__global__ __launch_bounds__(512, 1) void attn_kernel(
    const unsigned short* __restrict__ Qb,   // [B][N][II] fp16 (pre-scaled by log2e)
    const unsigned short* __restrict__ Kb,   // [B][N][II] fp16
    const unsigned short* __restrict__ Vb,   // [B][II][N] fp16
    unsigned short* __restrict__ Yp,         // [NSPLIT][B][N][II] fp16 normalized partial
    float2* __restrict__ ML)                 // [NSPLIT][B][N] {m,l} (base-2 domain)
{
    __shared__ unsigned short Ks[2][64 * 128];   // dbuf K (32 KB)
    __shared__ unsigned short Vs[2][128 * 64];   // dbuf V^T, permuted cols (32 KB)

    int tid = threadIdx.x;
    int w = tid >> 6, l = tid & 63, g = l >> 4, cl = l & 15;
    int id = blockIdx.x;
    int comb = (id & 7) * 2 + ((id >> 3) & 1);
    int b = comb >> 2, sp = comb & 3, qt = id >> 4;
    int qr0 = qt * 256;
    int m_base = sp * KVH;

    f16x8 qa0[4], qa1[4];
    {
        const unsigned short* qrow0 = Qb + (size_t)(b * NN + qr0 + w * 32 + cl) * II;
        const unsigned short* qrow1 = qrow0 + 16 * II;
        #pragma unroll
        for (int kc = 0; kc < 4; ++kc) {
            qa0[kc] = *(const f16x8*)(qrow0 + kc * 32 + g * 8);
            qa1[kc] = *(const f16x8*)(qrow1 + kc * 32 + g * 8);
        }
    }
    const f16x8 onesv = {(_Float16)1.f, (_Float16)1.f, (_Float16)1.f, (_Float16)1.f,
                         (_Float16)1.f, (_Float16)1.f, (_Float16)1.f, (_Float16)1.f};

    f32x4 yacc0[8], yacc1[8], lacc0, lacc1;
    #pragma unroll
    for (int it = 0; it < 8; ++it) {
        yacc0[it] = (f32x4){0.f, 0.f, 0.f, 0.f};
        yacc1[it] = (f32x4){0.f, 0.f, 0.f, 0.f};
    }
    lacc0 = (f32x4){0.f, 0.f, 0.f, 0.f};
    lacc1 = (f32x4){0.f, 0.f, 0.f, 0.f};
    float mrun0 = -1e30f, mrun1 = -1e30f;

    const unsigned short* kb = Kb + (size_t)(b * NN + m_base) * II;
    const unsigned short* vb = Vb + (size_t)b * II * NN + m_base;
    int krow = tid >> 4, kch = tid & 15;     // krow 0..31
    int vrow = tid >> 3, vch = tid & 7;      // vrow 0..63
    int kswz = (kch ^ (krow & 7)) << 4;
    int vsw = (vrow & 7) << 4;
    int vc0 = ((vch >> 2) * 32 + (vch & 1) * 16 + ((vch >> 1) & 1) * 4) * 2;

    uint4 k0, k1, v0, v1;
    k0 = *(const uint4*)(kb + (size_t)(krow) * II + kch * 8);
    k1 = *(const uint4*)(kb + (size_t)(32 + krow) * II + kch * 8);
    v0 = *(const uint4*)(vb + (size_t)(vrow) * NN + vch * 8);
    v1 = *(const uint4*)(vb + (size_t)(64 + vrow) * NN + vch * 8);
    {
        *(uint4*)((char*)Ks[0] + (krow) * 256 + kswz) = k0;
        *(uint4*)((char*)Ks[0] + (32 + krow) * 256 + kswz) = k1;
        uint2 lo, hi;
        lo.x = v0.x; lo.y = v0.y; hi.x = v0.z; hi.y = v0.w;
        *(uint2*)((char*)Vs[0] + (vrow) * 128 + (vc0 ^ vsw)) = lo;
        *(uint2*)((char*)Vs[0] + (vrow) * 128 + ((vc0 + 16) ^ vsw)) = hi;
        lo.x = v1.x; lo.y = v1.y; hi.x = v1.z; hi.y = v1.w;
        *(uint2*)((char*)Vs[0] + (64 + vrow) * 128 + (vc0 ^ vsw)) = lo;
        *(uint2*)((char*)Vs[0] + (64 + vrow) * 128 + ((vc0 + 16) ^ vsw)) = hi;
    }

    for (int t = 0; t < NT; ++t) {
        __syncthreads();
        const unsigned short* ksb = Ks[t & 1];
        const unsigned short* vsb = Vs[t & 1];
        unsigned short* kw = Ks[(t + 1) & 1];
        unsigned short* vw = Vs[(t + 1) & 1];
        bool more = (t + 1 < NT);
        if (more) {
            const unsigned short* kp = kb + (size_t)(t + 1) * 64 * II;
            const unsigned short* vp = vb + (size_t)(t + 1) * 64;
            k0 = *(const uint4*)(kp + (size_t)(krow) * II + kch * 8);
            k1 = *(const uint4*)(kp + (size_t)(32 + krow) * II + kch * 8);
            v0 = *(const uint4*)(vp + (size_t)(vrow) * NN + vch * 8);
            v1 = *(const uint4*)(vp + (size_t)(64 + vrow) * NN + vch * 8);
        }

        // ---- S^T = K Q^T for both q-groups ----
        f32x4 s0[4], s1[4];
        #pragma unroll
        for (int mt = 0; mt < 4; ++mt) {
            s0[mt] = (f32x4){0.f, 0.f, 0.f, 0.f};
            s1[mt] = (f32x4){0.f, 0.f, 0.f, 0.f};
        }
        __builtin_amdgcn_s_setprio(1);
        #pragma unroll
        for (int mt = 0; mt < 4; ++mt) {
            int row = mt * 16 + cl;
            #pragma unroll
            for (int kc = 0; kc < 4; ++kc) {
                f16x8 kf = *(const f16x8*)((const char*)ksb + row * 256 + (((kc * 4 + g) ^ (row & 7)) << 4));
                s0[mt] = __builtin_amdgcn_mfma_f32_16x16x32_f16(kf, qa0[kc], s0[mt], 0, 0, 0);
                s1[mt] = __builtin_amdgcn_mfma_f32_16x16x32_f16(kf, qa1[kc], s1[mt], 0, 0, 0);
            }
        }
        __builtin_amdgcn_s_setprio(0);

        // write next K tile mid-stream (K regs die; different buffer than ksb)
        if (more) {
            *(uint4*)((char*)kw + (krow) * 256 + kswz) = k0;
            *(uint4*)((char*)kw + (32 + krow) * 256 + kswz) = k1;
        }

        // ---- softmax q-group 0 ----
        union { unsigned int u[4]; f16x8 v; } pb00, pb01, pb10, pb11;
        {
            float t0 = M3(s0[0][0], s0[0][1], s0[0][2]);
            float t1 = M3(s0[0][3], s0[1][0], s0[1][1]);
            float t2 = M3(s0[1][2], s0[1][3], s0[2][0]);
            float t3 = M3(s0[2][1], s0[2][2], s0[2][3]);
            float t4 = M3(s0[3][0], s0[3][1], s0[3][2]);
            float tmax = fmaxf(M3(t0, t1, t2), M3(t3, t4, s0[3][3]));
            tmax = fmaxf(tmax, __shfl_xor(tmax, 16));
            tmax = fmaxf(tmax, __shfl_xor(tmax, 32));
            if (!__all(tmax <= mrun0 + 8.0f)) {
                float mnew = fmaxf(mrun0, tmax);
                float corr = exp2f(mrun0 - mnew);
                mrun0 = mnew;
                #pragma unroll
                for (int it = 0; it < 8; ++it)
                    #pragma unroll
                    for (int r = 0; r < 4; ++r) yacc0[it][r] *= corr;
                #pragma unroll
                for (int r = 0; r < 4; ++r) lacc0[r] *= corr;
            }
            #pragma unroll
            for (int mt = 0; mt < 4; ++mt) {
                unsigned int ua = cvt2h(exp2f(s0[mt][0] - mrun0), exp2f(s0[mt][1] - mrun0));
                unsigned int ub = cvt2h(exp2f(s0[mt][2] - mrun0), exp2f(s0[mt][3] - mrun0));
                if (mt < 2) { pb00.u[mt * 2] = ua; pb00.u[mt * 2 + 1] = ub; }
                else        { pb01.u[(mt - 2) * 2] = ua; pb01.u[(mt - 2) * 2 + 1] = ub; }
            }
        }

        // ---- PV group 0 (MFMA pipe) issued BEFORE softmax group 1 (VALU/trans):
        // independent streams -> group-1 VALU issues while group-0 MFMAs drain.
        __builtin_amdgcn_s_setprio(1);
        lacc0 = __builtin_amdgcn_mfma_f32_16x16x32_f16(onesv, pb00.v, lacc0, 0, 0, 0);
        lacc0 = __builtin_amdgcn_mfma_f32_16x16x32_f16(onesv, pb01.v, lacc0, 0, 0, 0);
        #pragma unroll
        for (int it = 0; it < 8; ++it) {
            int row = it * 16 + cl;
            f16x8 vf0 = *(const f16x8*)((const char*)vsb + row * 128 + ((g ^ (row & 7)) << 4));
            f16x8 vf1 = *(const f16x8*)((const char*)vsb + row * 128 + (((4 + g) ^ (row & 7)) << 4));
            yacc0[it] = __builtin_amdgcn_mfma_f32_16x16x32_f16(vf0, pb00.v, yacc0[it], 0, 0, 0);
            yacc0[it] = __builtin_amdgcn_mfma_f32_16x16x32_f16(vf1, pb01.v, yacc0[it], 0, 0, 0);
        }
        __builtin_amdgcn_s_setprio(0);

        // ---- softmax q-group 1 (overlaps group-0 PV drain) ----
        {
            float t0 = M3(s1[0][0], s1[0][1], s1[0][2]);
            float t1 = M3(s1[0][3], s1[1][0], s1[1][1]);
            float t2 = M3(s1[1][2], s1[1][3], s1[2][0]);
            float t3 = M3(s1[2][1], s1[2][2], s1[2][3]);
            float t4 = M3(s1[3][0], s1[3][1], s1[3][2]);
            float tmax = fmaxf(M3(t0, t1, t2), M3(t3, t4, s1[3][3]));
            tmax = fmaxf(tmax, __shfl_xor(tmax, 16));
            tmax = fmaxf(tmax, __shfl_xor(tmax, 32));
            if (!__all(tmax <= mrun1 + 8.0f)) {
                float mnew = fmaxf(mrun1, tmax);
                float corr = exp2f(mrun1 - mnew);
                mrun1 = mnew;
                #pragma unroll
                for (int it = 0; it < 8; ++it)
                    #pragma unroll
                    for (int r = 0; r < 4; ++r) yacc1[it][r] *= corr;
                #pragma unroll
                for (int r = 0; r < 4; ++r) lacc1[r] *= corr;
            }
            #pragma unroll
            for (int mt = 0; mt < 4; ++mt) {
                unsigned int ua = cvt2h(exp2f(s1[mt][0] - mrun1), exp2f(s1[mt][1] - mrun1));
                unsigned int ub = cvt2h(exp2f(s1[mt][2] - mrun1), exp2f(s1[mt][3] - mrun1));
                if (mt < 2) { pb10.u[mt * 2] = ua; pb10.u[mt * 2 + 1] = ub; }
                else        { pb11.u[(mt - 2) * 2] = ua; pb11.u[(mt - 2) * 2 + 1] = ub; }
            }
        }

        // write next V tile (different buffer than vsb; completes before next barrier)
        if (more) {
            uint2 lo, hi;
            lo.x = v0.x; lo.y = v0.y; hi.x = v0.z; hi.y = v0.w;
            *(uint2*)((char*)vw + (vrow) * 128 + (vc0 ^ vsw)) = lo;
            *(uint2*)((char*)vw + (vrow) * 128 + ((vc0 + 16) ^ vsw)) = hi;
            lo.x = v1.x; lo.y = v1.y; hi.x = v1.z; hi.y = v1.w;
            *(uint2*)((char*)vw + (64 + vrow) * 128 + (vc0 ^ vsw)) = lo;
            *(uint2*)((char*)vw + (64 + vrow) * 128 + ((vc0 + 16) ^ vsw)) = hi;
        }

        // ---- PV group 1 ----
        __builtin_amdgcn_s_setprio(1);
        lacc1 = __builtin_amdgcn_mfma_f32_16x16x32_f16(onesv, pb10.v, lacc1, 0, 0, 0);
        lacc1 = __builtin_amdgcn_mfma_f32_16x16x32_f16(onesv, pb11.v, lacc1, 0, 0, 0);
        #pragma unroll
        for (int it = 0; it < 8; ++it) {
            int row = it * 16 + cl;
            f16x8 vf0 = *(const f16x8*)((const char*)vsb + row * 128 + ((g ^ (row & 7)) << 4));
            f16x8 vf1 = *(const f16x8*)((const char*)vsb + row * 128 + (((4 + g) ^ (row & 7)) << 4));
            yacc1[it] = __builtin_amdgcn_mfma_f32_16x16x32_f16(vf0, pb10.v, yacc1[it], 0, 0, 0);
            yacc1[it] = __builtin_amdgcn_mfma_f32_16x16x32_f16(vf1, pb11.v, yacc1[it], 0, 0, 0);
        }
        __builtin_amdgcn_s_setprio(0);
    }

    __syncthreads();   // all waves done; Ks reusable as scratch

    unsigned short* ys = &Ks[0][w * 2048];   // 8 waves x 4KB = Ks[0]+Ks[1]
    size_t rowbase0 = (size_t)((sp * BB + b) * NN + qr0 + w * 32);
    int prow = l >> 2;
    {
        float rl = 1.0f / lacc0[0];
        #pragma unroll
        for (int it = 0; it < 8; ++it)
            #pragma unroll
            for (int r = 0; r < 4; r += 2) {
                int i = it * 16 + 4 * g + r;
                *(unsigned int*)((char*)ys + cl * 256 + ((i * 2) ^ ((cl & 7) << 4))) =
                    pack2h(yacc0[it][r] * rl, yacc0[it][r + 1] * rl);
            }
        #pragma unroll
        for (int c = 0; c < 4; ++c) {
            int seg = c * 4 + (l & 3);
            uint4 q = *(const uint4*)((const char*)ys + prow * 256 + ((seg << 4) ^ ((prow & 7) << 4)));
            *(uint4*)(Yp + (rowbase0 + prow) * II + seg * 8) = q;
        }
    }
    {
        float rl = 1.0f / lacc1[0];
        #pragma unroll
        for (int it = 0; it < 8; ++it)
            #pragma unroll
            for (int r = 0; r < 4; r += 2) {
                int i = it * 16 + 4 * g + r;
                *(unsigned int*)((char*)ys + cl * 256 + ((i * 2) ^ ((cl & 7) << 4))) =
                    pack2h(yacc1[it][r] * rl, yacc1[it][r + 1] * rl);
            }
        #pragma unroll
        for (int c = 0; c < 4; ++c) {
            int seg = c * 4 + (l & 3);
            uint4 q = *(const uint4*)((const char*)ys + prow * 256 + ((seg << 4) ^ ((prow & 7) << 4)));
            *(uint4*)(Yp + (rowbase0 + 16 + prow) * II + seg * 8) = q;
        }
    }
    if (l < 16) {
        float2 v; v.x = mrun0; v.y = lacc0[0];
        ML[rowbase0 + l] = v;
    } else if (l < 32) {
        float2 v; v.x = mrun1; v.y = lacc1[0];
        ML[rowbase0 + 16 + (l - 16)] = v;
    }
}

// ---------------- combine: grid (NN/32, BB); wave: q-half = w&1, ct-half = w>>1 ----------------
__global__ __launch_bounds__(256) void combine_kernel(
    const unsigned short* __restrict__ Yp, const float2* __restrict__ ML,
    const unsigned short* __restrict__ Wo, const float* __restrict__ b_out,
    const float* __restrict__ x, float* __restrict__ out)
{
    __shared__ unsigned short Ys[4][16 * 128];

    int tid = threadIdx.x;
    int w = tid >> 6, l = tid & 63, g = l >> 4, cl = l & 15;
    int qt = blockIdx.x, b = blockIdx.y;
    int n = qt * 32 + (w & 1) * 16 + cl;
    int ct0 = (w >> 1) * 8;

    float ms[NSPLIT], ls[NSPLIT], wgt[NSPLIT];
    float M = -1e30f;
    #pragma unroll
    for (int s = 0; s < NSPLIT; ++s) {
        float2 ml = ML[(size_t)(s * BB + b) * NN + n];
        ms[s] = ml.x; ls[s] = ml.y;
        M = fmaxf(M, ml.x);
    }
    float wsum = 0.f;
    #pragma unroll
    for (int s = 0; s < NSPLIT; ++s) { wgt[s] = exp2f(ms[s] - M) * ls[s]; wsum += wgt[s]; }
    float rd = 1.0f / wsum;
    #pragma unroll
    for (int s = 0; s < NSPLIT; ++s) wgt[s] *= rd;

    unsigned short* ys = Ys[w];
    #pragma unroll
    for (int j = 0; j < 4; ++j) {
        float acc[8];
        #pragma unroll
        for (int e = 0; e < 8; ++e) acc[e] = 0.f;
        #pragma unroll
        for (int s = 0; s < NSPLIT; ++s) {
            union { unsigned short s16[8]; uint4 q; } a;
            a.q = *(const uint4*)(Yp + ((size_t)(s * BB + b) * NN + n) * II + g * 32 + j * 8);
            #pragma unroll
            for (int e = 0; e < 8; ++e) acc[e] += wgt[s] * h2f(a.s16[e]);
        }
        union { unsigned int u[4]; uint4 q; } o;
        #pragma unroll
        for (int e = 0; e < 4; ++e) o.u[e] = pack2h(acc[e * 2], acc[e * 2 + 1]);
        *(uint4*)((char*)ys + cl * 256 + (((g * 4 + j) ^ (cl & 7)) << 4)) = o.q;
    }
    // same-wave write->read; no barrier needed

    f32x4 zero4 = {0.f, 0.f, 0.f, 0.f};
    f16x8 yf[4];
    #pragma unroll
    for (int kc = 0; kc < 4; ++kc)
        yf[kc] = *(const f16x8*)((const char*)ys + cl * 256 + (((kc * 4 + g) ^ (cl & 7)) << 4));
    for (int ct = ct0; ct < ct0 + 8; ++ct) {
        f32x4 oa = zero4;
        #pragma unroll
        for (int kc = 0; kc < 4; ++kc) {
            f16x8 wf = *(const f16x8*)(Wo + (ct * 16 + cl) * II + kc * 32 + g * 8);
            oa = __builtin_amdgcn_mfma_f32_16x16x32_f16(wf, yf[kc], oa, 0, 0, 0);
        }
        #pragma unroll
        for (int r = 0; r < 4; ++r) {
            int c = ct * 16 + 4 * g + r;
            size_t off = (size_t)(b * CC + c) * NN + n;
            out[off] = oa[r] + b_out[c] + x[off];
        }
    }
}

extern "C" void kernel_launch(void* const* d_in, const int* in_sizes, int n_in,
                              void* d_out, int out_size, void* d_ws, size_t ws_size,
                              hipStream_t stream) {
    const float* x     = (const float*)d_in[0];
    const float* w_g   = (const float*)d_in[1];
    const float* b_g   = (const float*)d_in[2];
    const float* w_th  = (const float*)d_in[3];
    const float* b_th  = (const float*)d_in[4];
    const float* w_ph  = (const float*)d_in[5];
    const float* b_ph  = (const float*)d_in[6];
    const float* w_out = (const float*)d_in[7];
    const float* b_o   = (const float*)d_in[8];
    float* out = (float*)d_out;

    const size_t SZ = (size_t)BB * NN * II;
    unsigned short* Qb = (unsigned short*)d_ws;
    unsigned short* Kb = Qb + SZ;
    unsigned short* Vt = Kb + SZ;
    unsigned short* Wo = Vt + SZ;
    unsigned short* Yp = Wo + (size_t)CC * II;                 // NSPLIT * SZ fp16
    float2*         ML = (float2*)(Yp + (size_t)NSPLIT * SZ);  // NSPLIT*B*N float2

    proj_kernel<<<dim3(NN / 64, BB, 3), dim3(256), 0, stream>>>(
        x, w_th, b_th, w_ph, b_ph, w_g, b_g, w_out, Qb, Kb, Vt, Wo);
    attn_kernel<<<dim3(NSPLIT * BB * (NN / 256)), dim3(512), 0, stream>>>(
        Qb, Kb, Vt, Yp, ML);
    combine_kernel<<<dim3(NN / 32, BB), dim3(256), 0, stream>>>(Yp, ML, Wo, b_o, x, out);
}